// Round 6
// baseline (43.617 us; speedup 1.0000x reference)
//
#include <hip/hip_runtime.h>

// PullbackMetric, 4 threads/pixel, direct-load design (no LDS staging).
// Exploits Si = Si^T (inverse of SPD):
//   X = dSx*Si, Y = dSy*Si  (thread s computes rows 2s,2s+1 of X,Y by dotting
//   its own dS rows with Si rows streamed straight from global memory).
//   cov00*2 = sum X[i,k]X[k,i], cov01*2 = sum X[i,k]Y[k,i], cov11*2 = sum Y[i,k]Y[k,i]
// LDS used ONLY to transpose X,Y (16 b64 writes + 8 b128 reads per thread).
// Mean term computed fully (redundantly) per thread inside the Si-row stream.

constexpr int MSTRIDE = 68;   // 272 B slot stride, 16B-aligned

#define DIFF4(dst, off, A, B) \
    dst[(off)+0] = (A.x - B.x) * 0.5f; dst[(off)+1] = (A.y - B.y) * 0.5f; \
    dst[(off)+2] = (A.z - B.z) * 0.5f; dst[(off)+3] = (A.w - B.w) * 0.5f;

__global__ __launch_bounds__(256, 3) void pm6_kernel(
    const float* __restrict__ mu,
    const float* __restrict__ sigma,
    const float* __restrict__ sigma_inv,
    float* __restrict__ out)
{
    __shared__ float mA[64 * MSTRIDE];   // Xt, 17408 B
    __shared__ float mB[64 * MSTRIDE];   // Yt, 17408 B  (34816 B -> 4 blocks/CU)

    const int tid = threadIdx.x;
    const int s   = tid & 3;     // owns rows 2s, 2s+1
    const int p   = tid >> 2;    // pixel within block

    // XCD-aware chunked swizzle (4096 blocks, 8 XCDs)
    const int bid = blockIdx.x;
    const int swz = (bid & 7) * 512 + (bid >> 3);
    const int idx = swz * 64 + p;

    const int x = idx >> 9, y = idx & 511;
    const int ixp = (((x + 1) & 511) << 9) | y;
    const int ixm = (((x - 1) & 511) << 9) | y;
    const int iyp = (x << 9) | ((y + 1) & 511);
    const int iym = (x << 9) | ((y - 1) & 511);

    float* slotA = mA + p * MSTRIDE;
    float* slotB = mB + p * MSTRIDE;

    // ---------------- dS rows 2s,2s+1 (both directions), direct loads ----------------
    float dsx0[8], dsx1[8], dsy0[8], dsy1[8];
    {
        const float4* a = reinterpret_cast<const float4*>(sigma + (size_t)ixp * 64 + s * 16);
        const float4* b = reinterpret_cast<const float4*>(sigma + (size_t)ixm * 64 + s * 16);
        float4 a0 = a[0], a1 = a[1], a2 = a[2], a3 = a[3];
        float4 b0 = b[0], b1 = b[1], b2 = b[2], b3 = b[3];
        DIFF4(dsx0, 0, a0, b0); DIFF4(dsx0, 4, a1, b1);
        DIFF4(dsx1, 0, a2, b2); DIFF4(dsx1, 4, a3, b3);
    }
    {
        const float4* a = reinterpret_cast<const float4*>(sigma + (size_t)iyp * 64 + s * 16);
        const float4* b = reinterpret_cast<const float4*>(sigma + (size_t)iym * 64 + s * 16);
        float4 a0 = a[0], a1 = a[1], a2 = a[2], a3 = a[3];
        float4 b0 = b[0], b1 = b[1], b2 = b[2], b3 = b[3];
        DIFF4(dsy0, 0, a0, b0); DIFF4(dsy0, 4, a1, b1);
        DIFF4(dsy1, 0, a2, b2); DIFF4(dsy1, 4, a3, b3);
    }

    // ---------------- full dmu vectors (mu is small & cache-hot) ----------------
    float dmu0[8], dmu1[8];
    {
        const float4* mxp = reinterpret_cast<const float4*>(mu + (size_t)ixp * 8);
        const float4* mxm = reinterpret_cast<const float4*>(mu + (size_t)ixm * 8);
        const float4* myp = reinterpret_cast<const float4*>(mu + (size_t)iyp * 8);
        const float4* mym = reinterpret_cast<const float4*>(mu + (size_t)iym * 8);
        float4 a0 = mxp[0], a1 = mxp[1], b0 = mxm[0], b1 = mxm[1];
        float4 c0 = myp[0], c1 = myp[1], d0 = mym[0], d1 = mym[1];
        DIFF4(dmu0, 0, a0, b0); DIFF4(dmu0, 4, a1, b1);
        DIFF4(dmu1, 0, c0, d0); DIFF4(dmu1, 4, c1, d1);
    }

    // ---------------- stream Si rows: X,Y rows + full mean term ----------------
    // X0[k] = dot(dsx0, Si_row_k)  (= X[2s][k] via Si symmetry), etc.
    float X0[8], X1[8], Y0[8], Y1[8];
    float m00 = 0.f, m01 = 0.f, m11 = 0.f;
    {
        const float4* siq = reinterpret_cast<const float4*>(sigma_inv + (size_t)idx * 64);
        #pragma unroll
        for (int k = 0; k < 8; ++k) {
            float row[8];
            float4 r0 = siq[2 * k], r1 = siq[2 * k + 1];
            row[0] = r0.x; row[1] = r0.y; row[2] = r0.z; row[3] = r0.w;
            row[4] = r1.x; row[5] = r1.y; row[6] = r1.z; row[7] = r1.w;
            float x0 = 0.f, x1 = 0.f, y0 = 0.f, y1 = 0.f, t0 = 0.f, t1 = 0.f;
            #pragma unroll
            for (int j = 0; j < 8; ++j) {
                x0 = fmaf(dsx0[j], row[j], x0);
                x1 = fmaf(dsx1[j], row[j], x1);
                y0 = fmaf(dsy0[j], row[j], y0);
                y1 = fmaf(dsy1[j], row[j], y1);
                t0 = fmaf(row[j], dmu0[j], t0);
                t1 = fmaf(row[j], dmu1[j], t1);
            }
            X0[k] = x0; X1[k] = x1; Y0[k] = y0; Y1[k] = y1;
            m00 = fmaf(dmu0[k], t0, m00);   // dmu0^T Si dmu0
            m01 = fmaf(dmu0[k], t1, m01);   // dmu0^T Si dmu1
            m11 = fmaf(dmu1[k], t1, m11);   // dmu1^T Si dmu1
        }
    }

    // ---------------- transpose X,Y through LDS ----------------
    // Xt[k][2s..2s+1] = {X0[k], X1[k]} : conflict-free b64 writes
    #pragma unroll
    for (int k = 0; k < 8; ++k) {
        float2 vt; vt.x = X0[k]; vt.y = X1[k];
        float2 vu; vu.x = Y0[k]; vu.y = Y1[k];
        *reinterpret_cast<float2*>(slotA + k * 8 + 2 * s) = vt;
        *reinterpret_cast<float2*>(slotB + k * 8 + 2 * s) = vu;
    }

    __syncthreads();

    // ---------------- cov partials: own rows (regs) x transposed rows (LDS) ----------------
    float c00 = 0.f, c01 = 0.f, c11 = 0.f;
    {
        float xt0[8], xt1[8], yt0[8], yt1[8];
        *reinterpret_cast<float4*>(&xt0[0]) = *reinterpret_cast<const float4*>(slotA + (2*s)   * 8);
        *reinterpret_cast<float4*>(&xt0[4]) = *reinterpret_cast<const float4*>(slotA + (2*s)   * 8 + 4);
        *reinterpret_cast<float4*>(&xt1[0]) = *reinterpret_cast<const float4*>(slotA + (2*s+1) * 8);
        *reinterpret_cast<float4*>(&xt1[4]) = *reinterpret_cast<const float4*>(slotA + (2*s+1) * 8 + 4);
        *reinterpret_cast<float4*>(&yt0[0]) = *reinterpret_cast<const float4*>(slotB + (2*s)   * 8);
        *reinterpret_cast<float4*>(&yt0[4]) = *reinterpret_cast<const float4*>(slotB + (2*s)   * 8 + 4);
        *reinterpret_cast<float4*>(&yt1[0]) = *reinterpret_cast<const float4*>(slotB + (2*s+1) * 8);
        *reinterpret_cast<float4*>(&yt1[4]) = *reinterpret_cast<const float4*>(slotB + (2*s+1) * 8 + 4);
        // xt0[k] = X[k][2s], yt0[k] = Y[k][2s], ...
        #pragma unroll
        for (int k = 0; k < 8; ++k) {
            c00 = fmaf(X0[k], xt0[k], c00); c00 = fmaf(X1[k], xt1[k], c00);
            c01 = fmaf(X0[k], yt0[k], c01); c01 = fmaf(X1[k], yt1[k], c01);
            c11 = fmaf(Y0[k], yt0[k], c11); c11 = fmaf(Y1[k], yt1[k], c11);
        }
    }

    // ---------------- reduce cov over the 4 lanes, combine, write ----------------
    c00 += __shfl_xor(c00, 1); c00 += __shfl_xor(c00, 2);
    c01 += __shfl_xor(c01, 1); c01 += __shfl_xor(c01, 2);
    c11 += __shfl_xor(c11, 1); c11 += __shfl_xor(c11, 2);

    float g0 = m00 + 0.5f * c00;   // G[0][0]
    float g1 = m01 + 0.5f * c01;   // G[0][1] == G[1][0]
    float g3 = m11 + 0.5f * c11;   // G[1][1]

    float val = (s == 0) ? g0 : ((s == 3) ? g3 : g1);
    out[(size_t)idx * 4 + s] = val;
}

extern "C" void kernel_launch(void* const* d_in, const int* in_sizes, int n_in,
                              void* d_out, int out_size, void* d_ws, size_t ws_size,
                              hipStream_t stream) {
    const float* mu        = (const float*)d_in[0];
    const float* sigma     = (const float*)d_in[1];
    const float* sigma_inv = (const float*)d_in[2];
    float* out = (float*)d_out;

    // 262144 pixels * 4 threads / 256 = 4096 blocks (divisible by 8 -> bijective swizzle)
    pm6_kernel<<<4096, 256, 0, stream>>>(mu, sigma, sigma_inv, out);
}

// Round 7
// 39.508 us; speedup vs baseline: 1.1040x; 1.1040x over previous
//
#include <hip/hip_runtime.h>

// PullbackMetric, 4 threads/pixel. R7: R6 math + Si staged once per pixel in LDS.
//   X = dSx*Si, Y = dSy*Si (thread s computes rows 2s,2s+1; Si rows read from LDS
//   with all 4 quad lanes at the same address -> broadcast, conflict-free).
//   cov00 = sum X[i,k]X[k,i] etc. via transpose-through-LDS (Xt reuses Si buffer).
//   mean term computed redundantly per thread inside the Si-row stream.
// LDS/thread: 4 b128 w (Si) + 16 b128 r (stream) + 16 b64 w (Xt/Yt) + 8 b128 r (cov).

constexpr int MSTRIDE = 68;   // 272 B slot stride, 16B-aligned

#define DIFF4(dst, off, A, B) \
    dst[(off)+0] = (A.x - B.x) * 0.5f; dst[(off)+1] = (A.y - B.y) * 0.5f; \
    dst[(off)+2] = (A.z - B.z) * 0.5f; dst[(off)+3] = (A.w - B.w) * 0.5f;

__global__ __launch_bounds__(256, 4) void pm7_kernel(
    const float* __restrict__ mu,
    const float* __restrict__ sigma,
    const float* __restrict__ sigma_inv,
    float* __restrict__ out)
{
    __shared__ float mS[64 * MSTRIDE];   // Si, later Xt   (17408 B)
    __shared__ float mB[64 * MSTRIDE];   // Yt             (17408 B; total 34816 -> 4 blk/CU)

    const int tid = threadIdx.x;
    const int s   = tid & 3;     // owns rows 2s, 2s+1
    const int p   = tid >> 2;    // pixel within block

    // XCD-aware chunked swizzle (4096 blocks, 8 XCDs)
    const int bid = blockIdx.x;
    const int swz = (bid & 7) * 512 + (bid >> 3);
    const int idx = swz * 64 + p;

    const int x = idx >> 9, y = idx & 511;
    const int ixp = (((x + 1) & 511) << 9) | y;
    const int ixm = (((x - 1) & 511) << 9) | y;
    const int iyp = (x << 9) | ((y + 1) & 511);
    const int iym = (x << 9) | ((y - 1) & 511);

    float* slotS = mS + p * MSTRIDE;
    float* slotB = mB + p * MSTRIDE;

    // ---------------- stage Si own rows -> LDS (pass-through) ----------------
    {
        const float4* q = reinterpret_cast<const float4*>(sigma_inv + (size_t)idx * 64 + s * 16);
        float4 q0 = q[0], q1 = q[1], q2 = q[2], q3 = q[3];
        float4* wS = reinterpret_cast<float4*>(slotS + s * 16);
        wS[0] = q0; wS[1] = q1; wS[2] = q2; wS[3] = q3;
    }

    // ---------------- dS rows 2s,2s+1 (both directions), direct loads ----------------
    float dsx0[8], dsx1[8], dsy0[8], dsy1[8];
    {
        const float4* a = reinterpret_cast<const float4*>(sigma + (size_t)ixp * 64 + s * 16);
        const float4* b = reinterpret_cast<const float4*>(sigma + (size_t)ixm * 64 + s * 16);
        float4 a0 = a[0], a1 = a[1], a2 = a[2], a3 = a[3];
        float4 b0 = b[0], b1 = b[1], b2 = b[2], b3 = b[3];
        DIFF4(dsx0, 0, a0, b0); DIFF4(dsx0, 4, a1, b1);
        DIFF4(dsx1, 0, a2, b2); DIFF4(dsx1, 4, a3, b3);
    }
    {
        const float4* a = reinterpret_cast<const float4*>(sigma + (size_t)iyp * 64 + s * 16);
        const float4* b = reinterpret_cast<const float4*>(sigma + (size_t)iym * 64 + s * 16);
        float4 a0 = a[0], a1 = a[1], a2 = a[2], a3 = a[3];
        float4 b0 = b[0], b1 = b[1], b2 = b[2], b3 = b[3];
        DIFF4(dsy0, 0, a0, b0); DIFF4(dsy0, 4, a1, b1);
        DIFF4(dsy1, 0, a2, b2); DIFF4(dsy1, 4, a3, b3);
    }

    // ---------------- full dmu vectors (mu is small & cache-hot) ----------------
    float dmu0[8], dmu1[8];
    {
        const float4* mxp = reinterpret_cast<const float4*>(mu + (size_t)ixp * 8);
        const float4* mxm = reinterpret_cast<const float4*>(mu + (size_t)ixm * 8);
        const float4* myp = reinterpret_cast<const float4*>(mu + (size_t)iyp * 8);
        const float4* mym = reinterpret_cast<const float4*>(mu + (size_t)iym * 8);
        float4 a0 = mxp[0], a1 = mxp[1], b0 = mxm[0], b1 = mxm[1];
        float4 c0 = myp[0], c1 = myp[1], d0 = mym[0], d1 = mym[1];
        DIFF4(dmu0, 0, a0, b0); DIFF4(dmu0, 4, a1, b1);
        DIFF4(dmu1, 0, c0, d0); DIFF4(dmu1, 4, c1, d1);
    }

    __syncthreads();   // Si staged

    // ---------------- stream Si rows from LDS: X,Y rows + full mean term ----------------
    // X0[k] = dot(dsx0, Si_row_k) (= X[2s][k] via Si symmetry), etc.
    // All 4 quad lanes read the same address -> LDS broadcast, conflict-free.
    float X0[8], X1[8], Y0[8], Y1[8];
    float m00 = 0.f, m01 = 0.f, m11 = 0.f;
    #pragma unroll
    for (int k = 0; k < 8; ++k) {
        float row[8];
        *reinterpret_cast<float4*>(&row[0]) = *reinterpret_cast<const float4*>(slotS + k * 8);
        *reinterpret_cast<float4*>(&row[4]) = *reinterpret_cast<const float4*>(slotS + k * 8 + 4);
        float x0 = 0.f, x1 = 0.f, y0 = 0.f, y1 = 0.f, t0 = 0.f, t1 = 0.f;
        #pragma unroll
        for (int j = 0; j < 8; ++j) {
            x0 = fmaf(dsx0[j], row[j], x0);
            x1 = fmaf(dsx1[j], row[j], x1);
            y0 = fmaf(dsy0[j], row[j], y0);
            y1 = fmaf(dsy1[j], row[j], y1);
            t0 = fmaf(row[j], dmu0[j], t0);
            t1 = fmaf(row[j], dmu1[j], t1);
        }
        X0[k] = x0; X1[k] = x1; Y0[k] = y0; Y1[k] = y1;
        m00 = fmaf(dmu0[k], t0, m00);   // dmu0^T Si dmu0
        m01 = fmaf(dmu0[k], t1, m01);   // dmu0^T Si dmu1
        m11 = fmaf(dmu1[k], t1, m11);   // dmu1^T Si dmu1
    }

    __syncthreads();   // all Si reads done; safe to overwrite mS with Xt

    // ---------------- transpose X,Y through LDS (Xt -> mS, Yt -> mB) ----------------
    #pragma unroll
    for (int k = 0; k < 8; ++k) {
        float2 vt; vt.x = X0[k]; vt.y = X1[k];
        float2 vu; vu.x = Y0[k]; vu.y = Y1[k];
        *reinterpret_cast<float2*>(slotS + k * 8 + 2 * s) = vt;
        *reinterpret_cast<float2*>(slotB + k * 8 + 2 * s) = vu;
    }

    __syncthreads();   // Xt, Yt visible

    // ---------------- cov partials: own rows (regs) x transposed rows (LDS) ----------------
    float c00 = 0.f, c01 = 0.f, c11 = 0.f;
    {
        float xt0[8], xt1[8], yt0[8], yt1[8];
        *reinterpret_cast<float4*>(&xt0[0]) = *reinterpret_cast<const float4*>(slotS + (2*s)   * 8);
        *reinterpret_cast<float4*>(&xt0[4]) = *reinterpret_cast<const float4*>(slotS + (2*s)   * 8 + 4);
        *reinterpret_cast<float4*>(&xt1[0]) = *reinterpret_cast<const float4*>(slotS + (2*s+1) * 8);
        *reinterpret_cast<float4*>(&xt1[4]) = *reinterpret_cast<const float4*>(slotS + (2*s+1) * 8 + 4);
        *reinterpret_cast<float4*>(&yt0[0]) = *reinterpret_cast<const float4*>(slotB + (2*s)   * 8);
        *reinterpret_cast<float4*>(&yt0[4]) = *reinterpret_cast<const float4*>(slotB + (2*s)   * 8 + 4);
        *reinterpret_cast<float4*>(&yt1[0]) = *reinterpret_cast<const float4*>(slotB + (2*s+1) * 8);
        *reinterpret_cast<float4*>(&yt1[4]) = *reinterpret_cast<const float4*>(slotB + (2*s+1) * 8 + 4);
        // xt0[k] = X[k][2s], yt0[k] = Y[k][2s], ...
        #pragma unroll
        for (int k = 0; k < 8; ++k) {
            c00 = fmaf(X0[k], xt0[k], c00); c00 = fmaf(X1[k], xt1[k], c00);
            c01 = fmaf(X0[k], yt0[k], c01); c01 = fmaf(X1[k], yt1[k], c01);
            c11 = fmaf(Y0[k], yt0[k], c11); c11 = fmaf(Y1[k], yt1[k], c11);
        }
    }

    // ---------------- reduce cov over the 4 lanes, combine, write ----------------
    c00 += __shfl_xor(c00, 1); c00 += __shfl_xor(c00, 2);
    c01 += __shfl_xor(c01, 1); c01 += __shfl_xor(c01, 2);
    c11 += __shfl_xor(c11, 1); c11 += __shfl_xor(c11, 2);

    float g0 = m00 + 0.5f * c00;   // G[0][0]
    float g1 = m01 + 0.5f * c01;   // G[0][1] == G[1][0]
    float g3 = m11 + 0.5f * c11;   // G[1][1]

    float val = (s == 0) ? g0 : ((s == 3) ? g3 : g1);
    out[(size_t)idx * 4 + s] = val;
}

extern "C" void kernel_launch(void* const* d_in, const int* in_sizes, int n_in,
                              void* d_out, int out_size, void* d_ws, size_t ws_size,
                              hipStream_t stream) {
    const float* mu        = (const float*)d_in[0];
    const float* sigma     = (const float*)d_in[1];
    const float* sigma_inv = (const float*)d_in[2];
    float* out = (float*)d_out;

    // 262144 pixels * 4 threads / 256 = 4096 blocks (divisible by 8 -> bijective swizzle)
    pm7_kernel<<<4096, 256, 0, stream>>>(mu, sigma, sigma_inv, out);
}